// Round 7
// baseline (437.686 us; speedup 1.0000x reference)
//
#include <hip/hip_runtime.h>
#include <hip/hip_bf16.h>
#include <hip/hip_cooperative_groups.h>
#include <cstdint>
#include <cstddef>

namespace cg = cooperative_groups;

#define B_ 4
#define S_ 2048
#define T_ 2048
#define C_ 256
#define K2_ 512                       // interleaved hi/lo K
#define NEG_INF (-INFINITY)

typedef __attribute__((ext_vector_type(8)))  __bf16 bf16x8;
typedef __attribute__((ext_vector_type(16))) float  f32x16;

// C/D layout for mfma_f32_32x32x16_bf16 (m74/m101): col=lane&31,
// row = (reg&3) + 8*(reg>>2) + 4*(lane>>5)
#define ROWPAT(r, lh) (((r) & 3) + 8 * ((r) >> 2) + 4 * (lh))

typedef __attribute__((address_space(3))) unsigned       as3_u32;
typedef __attribute__((address_space(1))) const unsigned as1_u32;

__device__ __forceinline__ void gload16(const void* g, void* l) {
    __builtin_amdgcn_global_load_lds((as1_u32*)g, (as3_u32*)l, 16, 0, 0);
}

// f32 -> packed (hi bf16 | lo bf16) u32, RNE both stages; hi at low halfword
__device__ __forceinline__ unsigned pack_hl(float v) {
    __bf16 h = (__bf16)v;
    __bf16 l = (__bf16)(v - (float)h);
    unsigned short hu = __builtin_bit_cast(unsigned short, h);
    unsigned short lu = __builtin_bit_cast(unsigned short, l);
    return (unsigned)hu | ((unsigned)lu << 16);
}

// conf value; __noinline__ so phase-6 and phase-8 call the SAME code path and
// produce bit-identical results (mask equality compares depend on it).
__device__ __noinline__ float conf_fn(float a, float rm, float rs, float cm,
                                      float cs, int on) {
    float x = a * 10.f;                       // sim / TEMPERATURE
    float v = __expf(2.f * x - cm - rm) / (rs * cs);
    return on ? v : 0.f;
}

// ---------------------------------------------------------------------------
// Mask canonicalization (byte-bool vs 4-byte detection via element 1)
// ---------------------------------------------------------------------------
__global__ void build_masks_kernel(const void* __restrict__ src_mask,
                                   const void* __restrict__ tgt_mask,
                                   int* __restrict__ smask, int* __restrict__ tmask) {
    int i = blockIdx.x * blockDim.x + threadIdx.x;
    const unsigned char* sb = (const unsigned char*)src_mask;
    const unsigned char* tb = (const unsigned char*)tgt_mask;
    bool s_is_byte = (sb[1] != 0);
    bool t_is_byte = (tb[1] != 0);
    if (i < B_ * S_)
        smask[i] = s_is_byte ? (sb[i] != 0) : (((const int*)src_mask)[i] != 0);
    if (i < B_ * T_)
        tmask[i] = t_is_byte ? (tb[i] != 0) : (((const int*)tgt_mask)[i] != 0);
}

// ---------------------------------------------------------------------------
// One cooperative kernel: proj -> sim GEMM (once!) -> stats -> combine ->
// conf + maxima -> mask. 256 blocks x 512 thr, 1 block/CU.
// ---------------------------------------------------------------------------
__global__ __launch_bounds__(512, 2) void fused_kernel(
    const float* __restrict__ src_feats, const float* __restrict__ tgt_feats,
    const float* __restrict__ Wf,
    const int* __restrict__ smask, const int* __restrict__ tmask,
    unsigned* __restrict__ P2u,                 // [16384][256] u32 (packed hi/lo)
    float2* __restrict__ rowpart, float2* __restrict__ colpart,
    float2* __restrict__ rowstats, float2* __restrict__ colstats,
    unsigned* __restrict__ rowconfmax, unsigned* __restrict__ colconfmax,
    float* __restrict__ conf, float* __restrict__ maskoutp)
{
    __shared__ char lds[131072 + 256 * 4 * 2 + 256 * 8 * 2];
    char* bufs = lds;                                   // 128KB GEMM tiles
    int*    smask_lds = (int*)(lds + 131072);
    int*    tmask_lds = smask_lds + 256;
    float2* rstat_lds = (float2*)(tmask_lds + 256);
    float2* cstat_lds = rstat_lds + 256;

    const int tid = threadIdx.x;
    const int w = tid >> 6, lane = tid & 63;
    const int lr = lane & 31, lh = lane >> 5;

    // sim-tile mapping with XCD-aware swizzle (bijective for 256 blocks)
    const int lin = (blockIdx.x & 7) * 32 + (blockIdx.x >> 3);
    const int b = lin >> 6;
    const int rr = lin & 63;
    const int m0 = (rr >> 3) * 256;
    const int n0 = (rr & 7) * 256;
    const int wr = w >> 2, wc = w & 3;                  // wave grid 2 x 4

    if (tid < 256) smask_lds[tid] = smask[b * S_ + m0 + tid];
    else           tmask_lds[tid - 256] = tmask[b * T_ + n0 + (tid - 256)];

    // ===== phase 0: projection P = (feats @ W^T)/16, split fused in =====
    {
        char* pA = bufs;                 // 64 rows * 128B = 8KB
        char* pW = bufs + 8192;          // 256 rows * 128B = 32KB
        const int m0p = blockIdx.x * 64;
        const float* Fbase = (m0p < B_ * S_)
            ? (src_feats + (size_t)m0p * C_)
            : (tgt_feats + (size_t)(m0p - B_ * S_) * C_);
        f32x16 acc0[2] = {};
        for (int st = 0; st < 8; ++st) {
            {   // stage A (this block's 64 feat rows), f32 -> packed hi/lo
                int row = tid >> 3, c8 = tid & 7;
                float4 av = *(const float4*)(Fbase + (size_t)row * C_ +
                                             st * 32 + c8 * 4);
                uint4 p = make_uint4(pack_hl(av.x), pack_hl(av.y),
                                     pack_hl(av.z), pack_hl(av.w));
                *(uint4*)(pA + row * 128 + ((c8 ^ (row & 7)) * 16)) = p;
            }
            #pragma unroll
            for (int q = 0; q < 4; ++q) {   // stage W (L2-hot, re-split)
                int i = q * 512 + tid;
                int row = i >> 3, c8 = i & 7;
                float4 wv = *(const float4*)(Wf + (size_t)row * C_ +
                                             st * 32 + c8 * 4);
                uint4 p = make_uint4(pack_hl(wv.x), pack_hl(wv.y),
                                     pack_hl(wv.z), pack_hl(wv.w));
                *(uint4*)(pW + row * 128 + ((c8 ^ (row & 7)) * 16)) = p;
            }
            __syncthreads();
            #pragma unroll
            for (int ks = 0; ks < 4; ++ks) {
                const int cs = ks * 2 + lh;
                bf16x8 a0[2], bw, bs;
                #pragma unroll
                for (int fi = 0; fi < 2; ++fi) {
                    int row = fi * 32 + lr;
                    a0[fi] = *(const bf16x8*)(pA + row * 128 +
                                              ((cs ^ (row & 7)) * 16));
                }
                {
                    int row = w * 32 + lr;
                    bw = *(const bf16x8*)(pW + row * 128 +
                                          ((cs ^ (row & 7)) * 16));
                    bs = __builtin_shufflevector(bw, bw, 1, 0, 3, 2, 5, 4, 7, 6);
                }
                #pragma unroll
                for (int fi = 0; fi < 2; ++fi) {
                    acc0[fi] = __builtin_amdgcn_mfma_f32_32x32x16_bf16(
                        a0[fi], bw, acc0[fi], 0, 0, 0);
                    acc0[fi] = __builtin_amdgcn_mfma_f32_32x32x16_bf16(
                        a0[fi], bs, acc0[fi], 0, 0, 0);
                }
            }
            __syncthreads();
        }
        #pragma unroll
        for (int fi = 0; fi < 2; ++fi)
            #pragma unroll
            for (int r = 0; r < 16; ++r) {
                int row = m0p + fi * 32 + ROWPAT(r, lh);
                int col = w * 32 + lr;
                P2u[(size_t)row * 256 + col] = pack_hl(acc0[fi][r] * 0.0625f);
            }
    }
    cg::this_grid().sync();

    // ===== phase 1: the sim GEMM (computed ONCE, acc kept in registers) =====
    const __bf16* P2 = (const __bf16*)P2u;
    const __bf16* Ab = P2 + (size_t)(b * S_) * K2_;
    const __bf16* Bb = P2 + (size_t)(B_ * S_ + b * T_) * K2_;

    auto stage = [&](int st) {
        char* buf = bufs + (st & 1) * 65536;
        const int kb = st * 64;
        #pragma unroll
        for (int q = 0; q < 4; ++q) {
            int i = q * 512 + tid;
            int row = i >> 3, c = i & 7;
            int sc = c ^ (row & 7);
            gload16(Ab + (size_t)(m0 + row) * K2_ + kb + sc * 8,
                    buf + (q * 512 + w * 64) * 16);
        }
        char* bufB = buf + 32768;
        #pragma unroll
        for (int q = 0; q < 4; ++q) {
            int i = q * 512 + tid;
            int row = i >> 3, c = i & 7;
            int sc = c ^ (row & 7);
            gload16(Bb + (size_t)(n0 + row) * K2_ + kb + sc * 8,
                    bufB + (q * 512 + w * 64) * 16);
        }
    };

    f32x16 acc[4][2] = {};
    stage(0);
    __syncthreads();
    for (int st = 0; st < 8; ++st) {
        if (st < 7) stage(st + 1);
        const char* buf  = bufs + (st & 1) * 65536;
        const char* bufB = buf + 32768;
        #pragma unroll
        for (int ks = 0; ks < 4; ++ks) {
            const int cs = ks * 2 + lh;
            bf16x8 a[4], bv[2], bs[2];
            #pragma unroll
            for (int fi = 0; fi < 4; ++fi) {
                int row = wr * 128 + fi * 32 + lr;
                a[fi] = *(const bf16x8*)(buf + row * 128 + ((cs ^ (row & 7)) * 16));
            }
            #pragma unroll
            for (int fj = 0; fj < 2; ++fj) {
                int row = wc * 64 + fj * 32 + lr;
                bv[fj] = *(const bf16x8*)(bufB + row * 128 + ((cs ^ (row & 7)) * 16));
                bs[fj] = __builtin_shufflevector(bv[fj], bv[fj], 1, 0, 3, 2, 5, 4, 7, 6);
            }
            #pragma unroll
            for (int fi = 0; fi < 4; ++fi)
                #pragma unroll
                for (int fj = 0; fj < 2; ++fj)
                    acc[fi][fj] = __builtin_amdgcn_mfma_f32_32x32x16_bf16(
                        a[fi], bv[fj], acc[fi][fj], 0, 0, 0);   // hh + ll
            #pragma unroll
            for (int fi = 0; fi < 4; ++fi)
                #pragma unroll
                for (int fj = 0; fj < 2; ++fj)
                    acc[fi][fj] = __builtin_amdgcn_mfma_f32_32x32x16_bf16(
                        a[fi], bs[fj], acc[fi][fj], 0, 0, 0);   // hl + lh
        }
        __syncthreads();
    }

    // ===== phase 2: masked softmax stat partials =====
    {
        const int tm0 = tmask_lds[wc * 64 + lr];
        const int tm1 = tmask_lds[wc * 64 + 32 + lr];
        #pragma unroll
        for (int fi = 0; fi < 4; ++fi)
            #pragma unroll
            for (int r = 0; r < 16; ++r) {
                float v0 = tm0 ? acc[fi][0][r] * 10.f : NEG_INF;
                float v1 = tm1 ? acc[fi][1][r] * 10.f : NEG_INF;
                float m = fmaxf(v0, v1);
                #pragma unroll
                for (int off = 1; off <= 16; off <<= 1)
                    m = fmaxf(m, __shfl_xor(m, off));
                float e = 0.f;
                if (m > NEG_INF) e = __expf(v0 - m) + __expf(v1 - m);
                #pragma unroll
                for (int off = 1; off <= 16; off <<= 1)
                    e += __shfl_xor(e, off);
                if (lr == 0) {
                    int row = m0 + wr * 128 + fi * 32 + ROWPAT(r, lh);
                    rowpart[((size_t)(b * S_ + row)) * 32 + (n0 >> 6) + wc] =
                        make_float2(m, e);
                }
            }
        #pragma unroll
        for (int fj = 0; fj < 2; ++fj) {
            float m = NEG_INF;
            #pragma unroll
            for (int fi = 0; fi < 4; ++fi)
                #pragma unroll
                for (int r = 0; r < 16; ++r) {
                    int rl = wr * 128 + fi * 32 + ROWPAT(r, lh);
                    float x = smask_lds[rl] ? acc[fi][fj][r] * 10.f : NEG_INF;
                    m = fmaxf(m, x);
                }
            m = fmaxf(m, __shfl_xor(m, 32));
            float e = 0.f;
            if (m > NEG_INF) {
                #pragma unroll
                for (int fi = 0; fi < 4; ++fi)
                    #pragma unroll
                    for (int r = 0; r < 16; ++r) {
                        int rl = wr * 128 + fi * 32 + ROWPAT(r, lh);
                        float x = smask_lds[rl] ? acc[fi][fj][r] * 10.f : NEG_INF;
                        e += __expf(x - m);
                    }
            }
            e += __shfl_xor(e, 32);
            if (lh == 0) {
                int col = n0 + wc * 64 + fj * 32 + lr;
                colpart[((size_t)(b * T_ + col)) * 16 + (m0 >> 7) + wr] =
                    make_float2(m, e);
            }
        }
    }
    cg::this_grid().sync();

    // ===== phase 4: combine partials -> stats; zero conf maxima =====
    {
        const int bid = blockIdx.x;
        // rows: 16 groups of 32 lanes, 2 rows each
        #pragma unroll
        for (int rq = 0; rq < 2; ++rq) {
            int row = bid * 32 + (tid >> 5) * 2 + rq;
            float2 p = rowpart[(size_t)row * 32 + (tid & 31)];
            float M = p.x;
            #pragma unroll
            for (int off = 1; off <= 16; off <<= 1)
                M = fmaxf(M, __shfl_xor(M, off));
            float e = p.y * __expf(p.x - M);
            #pragma unroll
            for (int off = 1; off <= 16; off <<= 1)
                e += __shfl_xor(e, off);
            if ((tid & 31) == 0) rowstats[row] = make_float2(M, e);
        }
        // cols: 32 groups of 16 lanes, 1 col each
        {
            int col = bid * 32 + (tid >> 4);
            float2 p = colpart[(size_t)col * 16 + (tid & 15)];
            float M = p.x;
            #pragma unroll
            for (int off = 1; off <= 8; off <<= 1)
                M = fmaxf(M, __shfl_xor(M, off));
            float e = p.y * __expf(p.x - M);
            #pragma unroll
            for (int off = 1; off <= 8; off <<= 1)
                e += __shfl_xor(e, off);
            if ((tid & 15) == 0) colstats[col] = make_float2(M, e);
        }
        if (tid < 32)            rowconfmax[bid * 32 + tid] = 0u;
        else if (tid < 64)       colconfmax[bid * 32 + tid - 32] = 0u;
    }
    cg::this_grid().sync();

    // ===== phase 6: conf + row/col conf maxima =====
    if (tid < 256) rstat_lds[tid] = rowstats[b * S_ + m0 + tid];
    else           cstat_lds[tid - 256] = colstats[b * T_ + n0 + (tid - 256)];
    __syncthreads();
    const int tm0 = tmask_lds[wc * 64 + lr];
    const int tm1 = tmask_lds[wc * 64 + 32 + lr];
    const float2 cst0 = cstat_lds[wc * 64 + lr];
    const float2 cst1 = cstat_lds[wc * 64 + 32 + lr];
    {
        float* confb = conf + (size_t)b * S_ * T_;
        float cmax0 = 0.f, cmax1 = 0.f;
        #pragma unroll
        for (int fi = 0; fi < 4; ++fi)
            #pragma unroll
            for (int r = 0; r < 16; ++r) {
                int rl = wr * 128 + fi * 32 + ROWPAT(r, lh);
                float2 rst = rstat_lds[rl];
                int sm = smask_lds[rl];
                float cv0 = conf_fn(acc[fi][0][r], rst.x, rst.y, cst0.x, cst0.y,
                                    sm && tm0);
                float cv1 = conf_fn(acc[fi][1][r], rst.x, rst.y, cst1.x, cst1.y,
                                    sm && tm1);
                int rg = m0 + rl;
                int cg = n0 + wc * 64 + lr;
                confb[(size_t)rg * T_ + cg]      = cv0;
                confb[(size_t)rg * T_ + cg + 32] = cv1;
                float rmx = fmaxf(cv0, cv1);
                #pragma unroll
                for (int off = 1; off <= 16; off <<= 1)
                    rmx = fmaxf(rmx, __shfl_xor(rmx, off));
                if (lr == 0)
                    atomicMax(&rowconfmax[b * S_ + rg], __float_as_uint(rmx));
                cmax0 = fmaxf(cmax0, cv0);
                cmax1 = fmaxf(cmax1, cv1);
            }
        cmax0 = fmaxf(cmax0, __shfl_xor(cmax0, 32));
        cmax1 = fmaxf(cmax1, __shfl_xor(cmax1, 32));
        if (lh == 0) {
            int cg = n0 + wc * 64 + lr;
            atomicMax(&colconfmax[b * T_ + cg],      __float_as_uint(cmax0));
            atomicMax(&colconfmax[b * T_ + cg + 32], __float_as_uint(cmax1));
        }
    }
    cg::this_grid().sync();

    // ===== phase 8: mask from bit-identical recomputed conf =====
    {
        float* maskb = maskoutp + (size_t)b * S_ * T_;
        const int cg = n0 + wc * 64 + lr;
        const float cmax0f = __uint_as_float(colconfmax[b * T_ + cg]);
        const float cmax1f = __uint_as_float(colconfmax[b * T_ + cg + 32]);
        #pragma unroll
        for (int fi = 0; fi < 4; ++fi)
            #pragma unroll
            for (int r = 0; r < 16; ++r) {
                int rl = wr * 128 + fi * 32 + ROWPAT(r, lh);
                float2 rst = rstat_lds[rl];
                int sm = smask_lds[rl];
                int rg = m0 + rl;
                float rmaxf = __uint_as_float(rowconfmax[b * S_ + rg]);
                float cv0 = conf_fn(acc[fi][0][r], rst.x, rst.y, cst0.x, cst0.y,
                                    sm && tm0);
                float cv1 = conf_fn(acc[fi][1][r], rst.x, rst.y, cst1.x, cst1.y,
                                    sm && tm1);
                float o0 = (cv0 > 0.2f && cv0 == rmaxf && cv0 == cmax0f) ? 1.f : 0.f;
                float o1 = (cv1 > 0.2f && cv1 == rmaxf && cv1 == cmax1f) ? 1.f : 0.f;
                maskb[(size_t)rg * T_ + cg]      = o0;
                maskb[(size_t)rg * T_ + cg + 32] = o1;
            }
    }
}

extern "C" void kernel_launch(void* const* d_in, const int* in_sizes, int n_in,
                              void* d_out, int out_size, void* d_ws, size_t ws_size,
                              hipStream_t stream)
{
    const float* src_feats = (const float*)d_in[0];
    const float* tgt_feats = (const float*)d_in[1];
    const void*  src_mask  = d_in[2];
    const void*  tgt_mask  = d_in[3];
    const float* Wf        = (const float*)d_in[4];

    float* conf    = (float*)d_out;
    float* maskreg = conf + (size_t)B_ * S_ * T_;        // 64MB mask output

    // scratch inside the mask region (all consumed before phase 8 writes mask)
    const size_t MB = 1024 * 1024;
    unsigned* P2u     = (unsigned*)maskreg;                      // 16 MB
    float2*   rowpart = (float2*)((char*)maskreg + 16 * MB);     // 2 MB
    float2*   colpart = (float2*)((char*)maskreg + 18 * MB);     // 1 MB

    float2*   rowstats   = (float2*)d_ws;                    // B*S
    float2*   colstats   = rowstats + B_ * S_;               // B*T
    unsigned* rowconfmax = (unsigned*)(colstats + B_ * T_);  // B*S
    unsigned* colconfmax = rowconfmax + B_ * S_;             // B*T
    int*      smask      = (int*)(colconfmax + B_ * T_);     // B*S
    int*      tmask      = smask + B_ * S_;                  // B*T

    build_masks_kernel<<<32, 256, 0, stream>>>(src_mask, tgt_mask, smask, tmask);

    void* args[] = {
        (void*)&src_feats, (void*)&tgt_feats, (void*)&Wf,
        (void*)&smask, (void*)&tmask, (void*)&P2u,
        (void*)&rowpart, (void*)&colpart,
        (void*)&rowstats, (void*)&colstats,
        (void*)&rowconfmax, (void*)&colconfmax,
        (void*)&conf, (void*)&maskreg
    };
    hipLaunchCooperativeKernel((const void*)fused_kernel, dim3(256), dim3(512),
                               args, 0, stream);
}